// Round 1
// baseline (572.407 us; speedup 1.0000x reference)
//
#include <hip/hip_runtime.h>
#include <hip/hip_bf16.h>

// Problem: B=256, T=64, S=16, U=4.
// x: (B, T, S, S) fp32 ; W: (P=256, O=1024, K=64) fp32 ; bias: (256, 1024) fp32
// out: (B, T, 64, 64) fp32
// y[p,b,o] = sum_k x[b,k,p] * W[p,o,k] + bias[p,o]
// out[b][t][si*4+ui][sj*4+uj], o = t*16 + ui*4 + uj, p = si*16 + sj

#define P_PIX 256
#define BATCH 256
#define KDIM 64
#define ODIM 1024

using bf16x8 = __attribute__((ext_vector_type(8))) short;
using f32x4  = __attribute__((ext_vector_type(4))) float;

// ---------------- Kernel 1: transpose + convert x -> xp (P, B*T) bf16 ----------------
// x viewed as (R=16384, P=256) row-major; xp[p][r] = bf16(x[r][p]).
__global__ __launch_bounds__(256) void transpose_convert(
    const float* __restrict__ x, __hip_bfloat16* __restrict__ xp)
{
    __shared__ float tile[64][65];
    const int R = BATCH * KDIM;  // 16384
    int p0 = (blockIdx.x & 3) * 64;
    int r0 = (blockIdx.x >> 2) * 64;
    int tp = threadIdx.x & 63;
    int t4 = threadIdx.x >> 6;  // 0..3
    #pragma unroll
    for (int i = 0; i < 16; ++i) {
        int r = t4 + i * 4;
        tile[r][tp] = x[(size_t)(r0 + r) * P_PIX + p0 + tp];
    }
    __syncthreads();
    #pragma unroll
    for (int i = 0; i < 16; ++i) {
        int pl = t4 + i * 4;
        xp[(size_t)(p0 + pl) * R + r0 + tp] = __float2bfloat16(tile[tp][pl]);
    }
}

__device__ __forceinline__ bf16x8 cvt8(f32x4 a, f32x4 b) {
    __hip_bfloat16 h[8];
    h[0] = __float2bfloat16(a[0]); h[1] = __float2bfloat16(a[1]);
    h[2] = __float2bfloat16(a[2]); h[3] = __float2bfloat16(a[3]);
    h[4] = __float2bfloat16(b[0]); h[5] = __float2bfloat16(b[1]);
    h[6] = __float2bfloat16(b[2]); h[7] = __float2bfloat16(b[3]);
    return *(bf16x8*)h;
}

// ---------------- Kernel 2: swapped-operand per-pixel GEMM, lane-contiguous writes ----
// Block = (si, t, btile of 64 batches); 4 waves, each wave = 16 batches (MFMA cols).
// MFMA(W_frag, x_frag): C row = o' = quad*4+reg (so ui=quad, uj=reg), C col = batch.
// Lane (quad,lrow) accumulates over the 16 sj pixels the FULL 64-float output row
// out[b][t][si*4+quad][0..63]  ->  16 contiguous float4 stores per lane, zero
// partial-line write amplification. No LDS anywhere.
//
// Grid swizzle (grid=4096): xcd = id&7 (round-robin heuristic).
//   btile = (id>>3)&3  -> the 4 blocks sharing a 64 KB W slice sit 8 apart (same XCD,
//                         adjacent dispatch) -> W fetched once from HBM.
//   t = (u&7)*8 + xcd, si = u>>3 -> per XCD, 8 t's x 4 btiles of one si run together,
//                         keeping the 4x128 KB x slices L2-resident.
__global__ __launch_bounds__(256, 4) void gemm_pixel_t(
    const __hip_bfloat16* __restrict__ xp,  // (256 p, 256 b, 64 k) bf16
    const float* __restrict__ W,            // (256 p, 1024 o, 64 k) fp32
    const float* __restrict__ bias,         // (256 p, 1024 o) fp32
    float* __restrict__ out)                // (256 b, 64 t, 64, 64) fp32
{
    const int id    = blockIdx.x;
    const int xcd   = id & 7;
    const int l     = id >> 3;
    const int btile = l & 3;
    const int u     = l >> 2;            // 0..127
    const int si    = u >> 3;            // 0..15
    const int t     = (u & 7) * 8 + xcd; // 0..63
    const int tid   = threadIdx.x;
    const int wave  = tid >> 6;
    const int lane  = tid & 63;
    const int lrow  = lane & 15;
    const int quad  = lane >> 4;
    const int b     = btile * 64 + wave * 16 + lrow;  // this lane's batch (MFMA col)

    // x-side ("B" operand): lane holds xp[p][b][quad*8 + e (+32)]  (16 B bf16x8 loads)
    const __hip_bfloat16* xr0 = xp + (size_t)(si * 16) * (BATCH * KDIM)
                                   + (size_t)b * KDIM + quad * 8;
    // W-side ("A" operand): lane holds W[p][t*16 + lrow][quad*8 + e (+32)] fp32 -> bf16
    const float* wr0 = W + (size_t)(si * 16) * (ODIM * KDIM)
                         + (size_t)(t * 16 + lrow) * KDIM + quad * 8;
    // bias for rows o = t*16 + quad*4 + r (r = reg): one float4 per sj, quad-uniform
    const float* br0 = bias + (size_t)(si * 16) * ODIM + t * 16 + quad * 4;
    // output row base for this lane: out[b][t][si*4+quad][0]
    float* orow = out + ((size_t)b * 64 + t) * 4096 + (si * 4 + quad) * 64;

    #pragma unroll
    for (int g = 0; g < 2; ++g) {
        f32x4 acc[8];
        #pragma unroll
        for (int s = 0; s < 8; ++s) {
            const int sj = g * 8 + s;
            const __hip_bfloat16* xr = xr0 + (size_t)sj * (BATCH * KDIM);
            const float*          wr = wr0 + (size_t)sj * (ODIM * KDIM);
            bf16x8 xv0 = *(const bf16x8*)(xr);
            bf16x8 xv1 = *(const bf16x8*)(xr + 32);
            f32x4 w0 = *(const f32x4*)(wr);
            f32x4 w1 = *(const f32x4*)(wr + 4);
            f32x4 w2 = *(const f32x4*)(wr + 32);
            f32x4 w3 = *(const f32x4*)(wr + 36);
            f32x4 c = {};
            c = __builtin_amdgcn_mfma_f32_16x16x32_bf16(cvt8(w0, w1), xv0, c, 0, 0, 0);
            c = __builtin_amdgcn_mfma_f32_16x16x32_bf16(cvt8(w2, w3), xv1, c, 0, 0, 0);
            c += *(const f32x4*)(br0 + (size_t)sj * ODIM);
            acc[s] = c;
        }
        // 8 contiguous 16 B stores -> with g loop, lane covers its full 256 B row
        #pragma unroll
        for (int s = 0; s < 8; ++s) {
            *(f32x4*)(orow + (g * 8 + s) * 4) = acc[s];
        }
    }
}

extern "C" void kernel_launch(void* const* d_in, const int* in_sizes, int n_in,
                              void* d_out, int out_size, void* d_ws, size_t ws_size,
                              hipStream_t stream) {
    const float* x    = (const float*)d_in[0];
    const float* W    = (const float*)d_in[1];
    const float* bias = (const float*)d_in[2];
    float* out = (float*)d_out;
    __hip_bfloat16* xp = (__hip_bfloat16*)d_ws;  // 256*256*64*2 = 8 MB

    transpose_convert<<<1024, 256, 0, stream>>>(x, xp);
    gemm_pixel_t<<<4096, 256, 0, stream>>>(xp, W, bias, out);
}

// Round 2
// 468.473 us; speedup vs baseline: 1.2219x; 1.2219x over previous
//
#include <hip/hip_runtime.h>
#include <hip/hip_bf16.h>

// Problem: B=256, T=64, S=16, U=4.
// x: (B, T, S, S) fp32 ; W: (P=256, O=1024, K=64) fp32 ; bias: (256, 1024) fp32
// out: (B, T, 64, 64) fp32
// y[p,b,o] = sum_k x[b,k,p] * W[p,o,k] + bias[p,o]
// out[b][t][si*4+ui][sj*4+uj], o = t*16 + ui*4 + uj, p = si*16 + sj

#define P_PIX 256
#define BATCH 256
#define KDIM 64
#define ODIM 1024

using bf16x8 = __attribute__((ext_vector_type(8))) short;
using f32x4  = __attribute__((ext_vector_type(4))) float;

typedef __attribute__((address_space(1))) const void cv_as1;
typedef __attribute__((address_space(3))) void v_as3;

// ---------------- Kernel 1: transpose + convert x -> xp (P, B*T) bf16 ----------------
__global__ __launch_bounds__(256) void transpose_convert(
    const float* __restrict__ x, __hip_bfloat16* __restrict__ xp)
{
    __shared__ float tile[64][65];
    const int R = BATCH * KDIM;  // 16384
    int p0 = (blockIdx.x & 3) * 64;
    int r0 = (blockIdx.x >> 2) * 64;
    int tp = threadIdx.x & 63;
    int t4 = threadIdx.x >> 6;  // 0..3
    #pragma unroll
    for (int i = 0; i < 16; ++i) {
        int r = t4 + i * 4;
        tile[r][tp] = x[(size_t)(r0 + r) * P_PIX + p0 + tp];
    }
    __syncthreads();
    #pragma unroll
    for (int i = 0; i < 16; ++i) {
        int pl = t4 + i * 4;
        xp[(size_t)(p0 + pl) * R + r0 + tp] = __float2bfloat16(tile[tp][pl]);
    }
}

__device__ __forceinline__ bf16x8 cvt8(f32x4 a, f32x4 b) {
    __hip_bfloat16 h[8];
    h[0] = __float2bfloat16(a[0]); h[1] = __float2bfloat16(a[1]);
    h[2] = __float2bfloat16(a[2]); h[3] = __float2bfloat16(a[3]);
    h[4] = __float2bfloat16(b[0]); h[5] = __float2bfloat16(b[1]);
    h[6] = __float2bfloat16(b[2]); h[7] = __float2bfloat16(b[3]);
    return *(bf16x8*)h;
}

// ---------------- Kernel 3: LDS-staged GEMM + wave-local transpose epilogue ----------
// Block = (si, t, btile of 64 b). Loop sj 0..15, W double-buffered via global_load_lds.
// Epilogue: per 4-sj group, wave-private LDS transpose so each store INSTRUCTION has
// lanes 4i..4i+3 covering one full aligned 64B sector (instruction-granule merging is
// the empirical requirement derived from v1=2.14x / v2=1.68x write amplification).
__global__ __launch_bounds__(256, 4) void gemm_pixel_v3(
    const __hip_bfloat16* __restrict__ xp,  // (256 p, 256 b, 64 k) bf16
    const float* __restrict__ W,            // (256 p, 1024 o, 64 k) fp32
    const float* __restrict__ bias,         // (256 p, 1024 o) fp32
    float* __restrict__ out)                // (256 b, 64 t, 64, 64) fp32
{
    // W tile: 16 rows (o) x 64 floats, stored as 256 x 16B chunks, XOR-swizzled source.
    __shared__ float wbuf[2][16 * 64];      // 2 x 4 KB
    // Wave-private C transpose scratch: 16 rows x 17 chunks (pad) x 16B = 4352 B/wave.
    __shared__ float cbuf[4][16 * 17 * 4];  // 17408 B

    const int id    = blockIdx.x;
    const int xcd   = id & 7;
    const int l     = id >> 3;
    const int btile = l & 3;
    const int u     = l >> 2;            // 0..127
    const int si    = u >> 3;            // 0..15
    const int t     = (u & 7) * 8 + xcd; // 0..63
    const int tid   = threadIdx.x;
    const int wave  = tid >> 6;
    const int lane  = tid & 63;
    const int lrow  = lane & 15;
    const int quad  = lane >> 4;
    const int b     = btile * 64 + wave * 16 + lrow;  // this lane's batch (MFMA col)

    const int sr = tid >> 4, sc = tid & 15;            // staging row/chunk
    const size_t wsrc_chunk = (size_t)(sr * 16 + (sc ^ sr)) * 4;  // src float offset

    f32x4  acc4[4];
    bf16x8 xA[2], xB[2];
    f32x4  bv[2];

    // ---- prologue: stage sj=0, prefetch x/bias sj=0 ----
    {
        const float* ws = W + ((size_t)(si * 16 + 0) * ODIM + t * 16) * KDIM;
        __builtin_amdgcn_global_load_lds((cv_as1*)(ws + wsrc_chunk),
                                         (v_as3*)(&wbuf[0][tid * 4]), 16, 0, 0);
        const __hip_bfloat16* xs = xp + ((size_t)(si * 16 + 0) * BATCH + b) * KDIM + quad * 8;
        xA[0] = *(const bf16x8*)(xs);
        xB[0] = *(const bf16x8*)(xs + 32);
        bv[0] = *(const f32x4*)(bias + (size_t)(si * 16 + 0) * ODIM + t * 16 + quad * 4);
    }

    #pragma unroll
    for (int sj = 0; sj < 16; ++sj) {
        const int pb = sj & 1;
        // Drains this wave's outstanding loads (incl. W_sj gll) + syncs the block.
        // W_{sj+1} gll issued AFTER this barrier stays in flight under compute sj.
        __syncthreads();
        if (sj < 15) {
            const float* ws = W + ((size_t)(si * 16 + sj + 1) * ODIM + t * 16) * KDIM;
            __builtin_amdgcn_global_load_lds((cv_as1*)(ws + wsrc_chunk),
                                             (v_as3*)(&wbuf[pb ^ 1][tid * 4]), 16, 0, 0);
            const __hip_bfloat16* xs = xp + ((size_t)(si * 16 + sj + 1) * BATCH + b) * KDIM + quad * 8;
            xA[pb ^ 1] = *(const bf16x8*)(xs);
            xB[pb ^ 1] = *(const bf16x8*)(xs + 32);
            bv[pb ^ 1] = *(const f32x4*)(bias + (size_t)(si * 16 + sj + 1) * ODIM + t * 16 + quad * 4);
        }
        // ---- compute sj from wbuf[pb] (swizzled chunks: lds(r, c_lin) = src(r, c_lin^r)) ----
        {
            const float* wb = wbuf[pb];
            f32x4 w00 = *(const f32x4*)(wb + (size_t)(lrow * 16 + ((quad * 2 + 0) ^ lrow)) * 4);
            f32x4 w01 = *(const f32x4*)(wb + (size_t)(lrow * 16 + ((quad * 2 + 1) ^ lrow)) * 4);
            f32x4 w10 = *(const f32x4*)(wb + (size_t)(lrow * 16 + ((quad * 2 + 8) ^ lrow)) * 4);
            f32x4 w11 = *(const f32x4*)(wb + (size_t)(lrow * 16 + ((quad * 2 + 9) ^ lrow)) * 4);
            f32x4 cc = {};
            cc = __builtin_amdgcn_mfma_f32_16x16x32_bf16(cvt8(w00, w01), xA[pb], cc, 0, 0, 0);
            cc = __builtin_amdgcn_mfma_f32_16x16x32_bf16(cvt8(w10, w11), xB[pb], cc, 0, 0, 0);
            acc4[sj & 3] = cc + bv[pb];
        }
        // ---- per-4-sj wave-local transpose epilogue ----
        if ((sj & 3) == 3) {
            const int g = sj >> 2;
            float* cb = &cbuf[wave][0];
            // write: data (b_off=lrow, row=quad, sjc=s2) at chunk lrow*17 + quad*4 + s2
            *(f32x4*)(cb + (size_t)(lrow * 17 + quad * 4 + 0) * 4) = acc4[0];
            *(f32x4*)(cb + (size_t)(lrow * 17 + quad * 4 + 1) * 4) = acc4[1];
            *(f32x4*)(cb + (size_t)(lrow * 17 + quad * 4 + 2) * 4) = acc4[2];
            *(f32x4*)(cb + (size_t)(lrow * 17 + quad * 4 + 3) * 4) = acc4[3];
            // read + store: instruction j covers 16 pieces of 64B, each by 4 adjacent lanes
            const int i4  = lane >> 2;   // 0..15
            const int cch = lane & 3;    // 16B chunk within the 64B piece (= sjc)
            #pragma unroll
            for (int j = 0; j < 4; ++j) {
                const int b_off = j * 4 + (i4 & 3);
                const int row   = i4 >> 2;
                f32x4 v = *(const f32x4*)(cb + (size_t)(b_off * 17 + row * 4 + cch) * 4);
                float* dst = out + ((size_t)(btile * 64 + wave * 16 + b_off) * 64 + t) * 4096
                                 + (si * 4 + row) * 64 + g * 16 + cch * 4;
                *(f32x4*)dst = v;
            }
        }
    }
}

extern "C" void kernel_launch(void* const* d_in, const int* in_sizes, int n_in,
                              void* d_out, int out_size, void* d_ws, size_t ws_size,
                              hipStream_t stream) {
    const float* x    = (const float*)d_in[0];
    const float* W    = (const float*)d_in[1];
    const float* bias = (const float*)d_in[2];
    float* out = (float*)d_out;
    __hip_bfloat16* xp = (__hip_bfloat16*)d_ws;  // 256*256*64*2 = 8 MB

    transpose_convert<<<1024, 256, 0, stream>>>(x, xp);
    gemm_pixel_v3<<<4096, 256, 0, stream>>>(xp, W, bias, out);
}